// Round 5
// baseline (154.441 us; speedup 1.0000x reference)
//
#include <hip/hip_runtime.h>
#include <hip/hip_bf16.h>
#include <cstdint>

typedef __attribute__((ext_vector_type(8))) short bf16x8;
typedef __attribute__((ext_vector_type(4))) float f32x4;

static __device__ __forceinline__ float lo16(uint32_t u){ return __uint_as_float(u << 16); }
static __device__ __forceinline__ float hi16(uint32_t u){ return __uint_as_float(u & 0xffff0000u); }
static __device__ __forceinline__ uint32_t f2bf(float x){
    uint32_t u = __float_as_uint(x);
    return (u + 0x7fffu + ((u >> 16) & 1u)) >> 16;
}
static __device__ __forceinline__ uint32_t pack2(float a, float b){
    return f2bf(a) | (f2bf(b) << 16);
}
static __device__ __forceinline__ uint32_t cvtpk(float a, float b){
    uint32_t r;
    asm("v_cvt_pk_bf16_f32 %0, %1, %2" : "=v"(r) : "v"(a), "v"(b));
    return r;
}
static __device__ __forceinline__ void pl32swap(uint32_t &x, uint32_t &y){
    asm("v_permlane32_swap_b32 %0, %1" : "+v"(x), "+v"(y));
}
static __device__ __forceinline__ void pl16swap(uint32_t &x, uint32_t &y){
    asm("v_permlane16_swap_b32 %0, %1" : "+v"(x), "+v"(y));
}
typedef const __attribute__((address_space(1))) uint32_t* gas_u32p;
typedef __attribute__((address_space(3))) uint32_t* las_u32p;
static __device__ __forceinline__ void gload_lds16(const uint32_t* g, uint32_t* l){
    __builtin_amdgcn_global_load_lds((gas_u32p)g, (las_u32p)l, 16, 0, 0);
}

// ---------------- K1: fused kf + qb projections + fp32 norm accumulation ------
// grid 512: blocks 0..255 = qb (bg, j-half), blocks 256..511 = kf (b, i-group)
// qb branch: NO LDS staging -- per-thread direct float4 global loads (lane-
// broadcast coalesced). Norms (knorm2 / qn2 / vsum) accumulated in fp32 via
// atomicAdd into pre-zeroed buffers, killing k_attn's prologue sweeps.
// Image layouts (consumed linearly by k_attn's global_load_lds):
//   kf_img[b][8192 u32]: i*16 + (((dp>>2)^(i&3))&3)*4 + (dp&3)
//   qb_img[bg][8192 u32]: d*256 + (((j>>3)^(d&7))&63)*4 + ((j&7)>>1)
__global__ __launch_bounds__(1024) void k_pre(const float* __restrict__ qg,
    const float* __restrict__ kg,
    const float* __restrict__ Wq, const float* __restrict__ bq,
    const float* __restrict__ Wk, const float* __restrict__ bk,
    uint32_t* __restrict__ qb_img, uint32_t* __restrict__ kf_img,
    float* __restrict__ kn2g, float* __restrict__ qn2g, float* __restrict__ vsg)
{
    __shared__ float buf[9248];
    int t = threadIdx.x;
    int blk = blockIdx.x;
    if (blk < 256){
        // ---------- qb projection (direct-global, no LDS) ----------
        int bg = blk >> 1, h = blk & 1;
        int b = bg >> 6, g = bg & 63;
        int bh = g >> 4, bw = (g >> 2) & 3, bd = g & 3;
        int d = t & 31, sub = t >> 5;          // sub 0..31
        const float* qbase = qg + (size_t)b * 1048576;
        float wq[32];
        #pragma unroll
        for (int c = 0; c < 32; ++c) wq[c] = Wq[c*32 + d];
        float bb = bq[d];
        uint32_t* qb_out = qb_img + (size_t)bg * 8192;
        float q2 = 0.f, vsum_ = 0.f;
        #pragma unroll
        for (int it = 0; it < 2; ++it){
            int jl = it*128 + sub*4;           // 4 consecutive j = one float4
            int ihl = jl >> 6, iw = (jl >> 3) & 7, f4 = (jl >> 2) & 1;
            const float* src = qbase + (bh*8 + h*4 + ihl)*1024
                             + (bw*8 + iw)*32 + bd*8 + f4*4;
            float a0 = bb, a1 = bb, a2 = bb, a3 = bb;
            #pragma unroll
            for (int c = 0; c < 32; ++c){
                float4 qv = *(const float4*)(src + c*32768);
                a0 += qv.x*wq[c]; a1 += qv.y*wq[c];
                a2 += qv.z*wq[c]; a3 += qv.w*wq[c];
            }
            q2 += a0*a0 + a1*a1 + a2*a2 + a3*a3;
            vsum_ += a0 + a1 + a2 + a3;
            int jg = h*256 + jl;
            int grp = ((jg>>3) ^ (d&7)) & 63;
            int word = (jg&7) >> 1;
            uint2 wv; wv.x = pack2(a0, a1); wv.y = pack2(a2, a3);
            *(uint2*)&qb_out[d*256 + grp*4 + word] = wv;
        }
        atomicAdd(&qn2g[bg*32 + d], q2);
        atomicAdd(&vsg[bg*32 + d], vsum_);
    } else {
        // ---------- kf projection ----------
        float* Wk_s = buf;            // 8192
        float* red  = buf + 8192;     // 1024 (32 x 32)
        for (int L = t; L < 8192; L += 1024) Wk_s[L] = Wk[L];
        __syncthreads();
        int kb_blk = blk - 256;
        int b = kb_blk >> 7, i0 = (kb_blk & 127) * 4;
        int d = t & 31, sub = t >> 5;
        int i = i0 + (sub >> 3);
        int cp = sub & 7;
        const float* kbp = kg + (size_t)b * 131072;
        float acc = 0.f;
        #pragma unroll 8
        for (int cc = 0; cc < 32; ++cc){
            int c = cp*32 + cc;
            acc += kbp[c*512 + i] * Wk_s[c*32 + d];
        }
        red[sub*32 + d] = acc;
        __syncthreads();
        if (t < 128){
            int isel = t >> 5, dd = t & 31;
            float s = bk[dd];
            #pragma unroll
            for (int cp2 = 0; cp2 < 8; ++cp2) s += red[(isel*8 + cp2)*32 + dd];
            atomicAdd(&kn2g[b*32 + dd], s*s);
            float sO = __shfl_xor(s, 1, 64);
            if ((dd & 1) == 0){
                int dp = dd >> 1;
                int ii = i0 + isel;
                kf_img[b*8192 + ii*16 + (((dp>>2) ^ (ii&3)) & 3)*4 + (dp&3)] = pack2(s, sO);
            }
        }
    }
}

// ---------------- K2: MFMA attention (no prologue sweeps) ----------
// grid 512 = (bg, j-quarter); block 512 = 8 waves; ~66 KB LDS -> 2 blocks/CU.
// Norms read from k_pre's fp32 accumulators. Swapped QK^T (A=kf,B=qb);
// exp+cvt_pk+permlane builds PV B-fragment in registers.
__global__ __launch_bounds__(512) void k_attn_mfma(const uint32_t* __restrict__ kf_img,
    const uint32_t* __restrict__ qb_img,
    const float* __restrict__ kn2g, const float* __restrict__ qn2g,
    const float* __restrict__ vsg,
    float* __restrict__ oraw, float* __restrict__ mnp, float* __restrict__ mxp)
{
    __shared__ uint32_t kfs32[8192];     // 32 KB: kf [512 i][16 dp] swizzled
    __shared__ uint16_t qbV16[16384];    // 32 KB: qb^T [32 d][512 i] swizzled
    __shared__ float mred[8][64];        // 2 KB
    __shared__ float vssh[32];
    __shared__ float denom_s;
    int t = threadIdx.x;
    int blk = blockIdx.x;
    int bg = blk >> 2, jq = blk & 3;
    int b = bg >> 6;
    int wave = t >> 6, lane = t & 63;
    // ---- stage kf + qbV: linear async copy of pre-swizzled images ----
    {
        const uint32_t* gk = kf_img + b*8192;
        const uint32_t* gq = qb_img + (size_t)bg*8192;
        uint32_t* lq = (uint32_t*)qbV16;
        #pragma unroll
        for (int m = 0; m < 4; ++m){
            int off = wave*1024 + m*256;             // u32 units; wave-uniform
            gload_lds16(gk + off + lane*4, kfs32 + off);
        }
        #pragma unroll
        for (int m = 0; m < 4; ++m){
            int off = wave*1024 + m*256;
            gload_lds16(gq + off + lane*4, lq + off);
        }
    }
    // ---- denom / vsum from precomputed norms ----
    if (t < 32){
        float kn = kn2g[b*32 + t];
        float q2 = qn2g[bg*32 + t];
        vssh[t] = vsg[bg*32 + t];
        float dv = sqrtf(kn) * sqrtf(q2);
        dv += __shfl_xor(dv, 1, 64);
        dv += __shfl_xor(dv, 2, 64);
        dv += __shfl_xor(dv, 4, 64);
        dv += __shfl_xor(dv, 8, 64);
        dv += __shfl_xor(dv, 16, 64);
        if (t == 0) denom_s = dv + 1e-4f;
    }
    __syncthreads();                     // drains gload_lds + publishes denom
    float rden = 1.0f / denom_s;
    int ln15 = lane & 15, quad = lane >> 4;
    float vs0[4], vs1[4];
    #pragma unroll
    for (int r = 0; r < 4; ++r){
        vs0[r] = vssh[quad*4 + r];
        vs1[r] = vssh[16 + quad*4 + r];
    }
    float* obase = oraw + (size_t)bg * 16384;
    int jloc = jq*128 + wave*16 + ln15;          // j within bg (0..511)
    union { bf16x8 v; uint16_t u[8]; } afr;
    #pragma unroll
    for (int jj = 0; jj < 8; ++jj){
        int d = quad*8 + jj;
        afr.u[jj] = qbV16[d*512 + (((jloc>>3) ^ (d&7)) & 63)*8 + (jloc&7)];
    }
    f32x4 pv0 = {0.f,0.f,0.f,0.f}, pv1 = {0.f,0.f,0.f,0.f};
    float pdn = 0.f;
    for (int sb = 0; sb < 4; ++sb){
        #pragma unroll
        for (int ch = 0; ch < 4; ++ch){
            int ib = sb*128 + ch*32;
            int i0 = ib + ln15;
            int i1 = i0 + 16;
            bf16x8 k0 = *(__shared__ bf16x8*)&kfs32[i0*16 + ((quad ^ (i0&3)) & 3)*4];
            bf16x8 k1 = *(__shared__ bf16x8*)&kfs32[i1*16 + ((quad ^ (i1&3)) & 3)*4];
            f32x4 z = {0.f,0.f,0.f,0.f};
            f32x4 s0 = __builtin_amdgcn_mfma_f32_16x16x32_bf16(k0, afr.v, z, 0, 0, 0);
            f32x4 s1 = __builtin_amdgcn_mfma_f32_16x16x32_bf16(k1, afr.v, z, 0, 0, 0);
            float e0[4], e1[4];
            #pragma unroll
            for (int r = 0; r < 4; ++r){
                float x = s0[r] * rden;
                e0[r] = x + x*x*(0.5f + x*(1.0f/6.0f));
                pdn += e0[r];
                x = s1[r] * rden;
                e1[r] = x + x*x*(0.5f + x*(1.0f/6.0f));
                pdn += e1[r];
            }
            uint32_t A0 = cvtpk(e0[0], e0[1]);
            uint32_t A1 = cvtpk(e0[2], e0[3]);
            uint32_t B0 = cvtpk(e1[0], e1[1]);
            uint32_t B1 = cvtpk(e1[2], e1[3]);
            pl32swap(A0, B0); pl16swap(A0, B0);
            pl32swap(A1, B1); pl16swap(A1, B1);
            union { bf16x8 v; uint32_t w[4]; } bp;
            bp.w[0] = A0; bp.w[1] = A1; bp.w[2] = B0; bp.w[3] = B1;
            int ig = ib + quad*8;
            int c0 = ln15, c1 = 16 + ln15;
            bf16x8 av0 = *(__shared__ bf16x8*)&qbV16[c0*512 + (((ig>>3) ^ (c0&7)) & 63)*8];
            bf16x8 av1 = *(__shared__ bf16x8*)&qbV16[c1*512 + (((ig>>3) ^ (c1&7)) & 63)*8];
            pv0 = __builtin_amdgcn_mfma_f32_16x16x32_bf16(av0, bp.v, pv0, 0, 0, 0);
            pv1 = __builtin_amdgcn_mfma_f32_16x16x32_bf16(av1, bp.v, pv1, 0, 0, 0);
        }
    }
    // ---- epilogue: denom (quad reduce), o write, min/max ----
    pdn += __shfl_xor(pdn, 16, 64);
    pdn += __shfl_xor(pdn, 32, 64);
    float rl = 1.0f / (512.f + pdn);
    float o0[4], o1[4];
    #pragma unroll
    for (int r = 0; r < 4; ++r){
        o0[r] = (vs0[r] + pv0[r]) * rl;
        o1[r] = (vs1[r] + pv1[r]) * rl;
        obase[(quad*4 + r)*512 + jloc]      = o0[r];
        obase[(16 + quad*4 + r)*512 + jloc] = o1[r];
    }
    #pragma unroll
    for (int r = 0; r < 4; ++r){
        float mnA = o0[r], mxA = o0[r], mnB = o1[r], mxB = o1[r];
        #pragma unroll
        for (int off = 1; off < 16; off <<= 1){
            mnA = fminf(mnA, __shfl_xor(mnA, off, 64));
            mxA = fmaxf(mxA, __shfl_xor(mxA, off, 64));
            mnB = fminf(mnB, __shfl_xor(mnB, off, 64));
            mxB = fmaxf(mxB, __shfl_xor(mxB, off, 64));
        }
        if (ln15 == 0){
            mred[wave][quad*4 + r]      = mnA;
            mred[wave][32 + quad*4 + r] = mxA;
            mred[wave][16 + quad*4 + r] = mnB;
            mred[wave][48 + quad*4 + r] = mxB;
        }
    }
    __syncthreads();
    if (t < 32){
        float mn = 3e38f, mx = -3e38f;
        #pragma unroll
        for (int w = 0; w < 8; ++w){
            mn = fminf(mn, mred[w][t]);
            mx = fmaxf(mx, mred[w][32 + t]);
        }
        int slot = (bg*4 + jq)*32 + t;
        mnp[slot] = mn;
        mxp[slot] = mx;
    }
}

// ---------------- K3: scrambled gather + fused renorm + Wp projection ----------------
// grid 2048; block 256; 32 positions/block, 4 gathers+outputs per thread
__global__ __launch_bounds__(256) void k_proj(const float* __restrict__ oraw,
    const float* __restrict__ mnp, const float* __restrict__ mxp,
    const float* __restrict__ Wp, const float* __restrict__ bp,
    float* __restrict__ out)
{
    __shared__ float Wp_s[1024], bp_s[32];
    __shared__ float sh_v[32][33];       // padded: kills 8-way bank conflict
    __shared__ float sh_o[32][33];
    int t = threadIdx.x;
    if (t < 32) bp_s[t] = bp[t];
    for (int L = t; L < 1024; L += 256) Wp_s[L] = Wp[L];
    int blk = blockIdx.x;
    int b = blk >> 10, p0 = (blk & 1023) * 32;
    int c = t & 31, ip0 = t >> 5;
    float vv[4];
    #pragma unroll
    for (int m = 0; m < 4; ++m){
        int p = p0 + m*8 + ip0;
        int h = p >> 10, w = (p >> 5) & 31, dsp = p & 31;
        int f = (h >> 3)*262144 + (w >> 3)*65536 + (dsp >> 3)*16384
              + (h & 7)*2048 + (w & 7)*256 + (dsp & 7)*32;
        int flat = f + c;
        int cidx = b*2048 + (flat >> 9);         // bg*32 + channel
        int s0 = ((cidx >> 5) << 7) + (cidx & 31);
        float o  = oraw[(size_t)b*1048576 + flat];
        float mn = fminf(fminf(mnp[s0], mnp[s0 + 32]), fminf(mnp[s0 + 64], mnp[s0 + 96]));
        float mx = fmaxf(fmaxf(mxp[s0], mxp[s0 + 32]), fmaxf(mxp[s0 + 64], mxp[s0 + 96]));
        vv[m] = (o - mn) / (mx - mn + 1e-4f);
    }
    __syncthreads();
    #pragma unroll
    for (int m = 0; m < 4; ++m) sh_v[m*8 + ip0][c] = vv[m];
    __syncthreads();
    #pragma unroll
    for (int m = 0; m < 4; ++m){
        int pos = m*8 + ip0;
        float acc = bp_s[c];
        #pragma unroll
        for (int cc = 0; cc < 32; ++cc)
            acc += sh_v[pos][cc] * Wp_s[cc*32 + c];
        sh_o[pos][c] = acc;
    }
    __syncthreads();
    #pragma unroll
    for (int m = 0; m < 4; ++m){
        int e = m*8 + (t >> 5), pi = t & 31;
        out[((size_t)(b*32 + e) << 15) + p0 + pi] = sh_o[pi][e];
    }
}

extern "C" void kernel_launch(void* const* d_in, const int* in_sizes, int n_in,
                              void* d_out, int out_size, void* d_ws, size_t ws_size,
                              hipStream_t stream)
{
    const float* q  = (const float*)d_in[0];
    const float* k  = (const float*)d_in[1];
    const float* Wq = (const float*)d_in[2];
    const float* bq = (const float*)d_in[3];
    const float* Wk = (const float*)d_in[4];
    const float* bk = (const float*)d_in[5];
    const float* Wp = (const float*)d_in[6];
    const float* bp = (const float*)d_in[7];

    float* base      = (float*)d_ws;
    uint32_t* kf_img = (uint32_t*)base;                // 16384 u32
    uint32_t* qb_img = (uint32_t*)(base + 16384);      // 1,048,576 u32
    float* oraw      = base + 1064960;                 // 2,097,152 f
    float* mnp       = base + 3162112;                 // 16384 f
    float* mxp       = base + 3178496;                 // 16384 f
    float* kn2g      = base + 3194880;                 // 64 f
    float* qn2g      = base + 3194944;                 // 4096 f
    float* vsg       = base + 3199040;                 // 4096 f (~12.8 MB total)
    float* outp      = (float*)d_out;

    hipMemsetAsync(kn2g, 0, (64 + 4096 + 4096) * sizeof(float), stream);
    hipLaunchKernelGGL(k_pre,       dim3(512),  dim3(1024), 0, stream, q, k, Wq, bq, Wk, bk,
                       qb_img, kf_img, kn2g, qn2g, vsg);
    hipLaunchKernelGGL(k_attn_mfma, dim3(512),  dim3(512),  0, stream, kf_img, qb_img,
                       kn2g, qn2g, vsg, oraw, mnp, mxp);
    hipLaunchKernelGGL(k_proj,      dim3(2048), dim3(256),  0, stream, oraw, mnp, mxp, Wp, bp, outp);
}

// Round 6
// 120.833 us; speedup vs baseline: 1.2781x; 1.2781x over previous
//
#include <hip/hip_runtime.h>
#include <hip/hip_bf16.h>
#include <cstdint>

typedef __attribute__((ext_vector_type(8))) short bf16x8;
typedef __attribute__((ext_vector_type(4))) float f32x4;

static __device__ __forceinline__ float lo16(uint32_t u){ return __uint_as_float(u << 16); }
static __device__ __forceinline__ float hi16(uint32_t u){ return __uint_as_float(u & 0xffff0000u); }
static __device__ __forceinline__ uint32_t f2bf(float x){
    uint32_t u = __float_as_uint(x);
    return (u + 0x7fffu + ((u >> 16) & 1u)) >> 16;
}
static __device__ __forceinline__ uint32_t pack2(float a, float b){
    return f2bf(a) | (f2bf(b) << 16);
}
static __device__ __forceinline__ uint32_t cvtpk(float a, float b){
    uint32_t r;
    asm("v_cvt_pk_bf16_f32 %0, %1, %2" : "=v"(r) : "v"(a), "v"(b));
    return r;
}
static __device__ __forceinline__ void pl32swap(uint32_t &x, uint32_t &y){
    asm("v_permlane32_swap_b32 %0, %1" : "+v"(x), "+v"(y));
}
static __device__ __forceinline__ void pl16swap(uint32_t &x, uint32_t &y){
    asm("v_permlane16_swap_b32 %0, %1" : "+v"(x), "+v"(y));
}
typedef const __attribute__((address_space(1))) uint32_t* gas_u32p;
typedef __attribute__((address_space(3))) uint32_t* las_u32p;
static __device__ __forceinline__ void gload_lds16(const uint32_t* g, uint32_t* l){
    __builtin_amdgcn_global_load_lds((gas_u32p)g, (las_u32p)l, 16, 0, 0);
}

// ---------------- K1: fused kf + qb projections + contention-free norm partials
// grid 512: blocks 0..255 = qb (bg, j-half, LDS-staged as in R3), 256..511 = kf.
// Each block writes UNIQUE partial slots (no atomics, no memset):
//   qn2p/vsp[(bg*2+h)*32 + d], kn2p[b*8192 + local*64 + w2*32 + d]
// Image layouts (consumed linearly by k_attn's global_load_lds):
//   kf_img[b][8192 u32]: i*16 + (((dp>>2)^(i&3))&3)*4 + (dp&3)
//   qb_img[bg][8192 u32]: d*256 + (((j>>3)^(d&7))&63)*4 + ((j&7)>>1)
__global__ __launch_bounds__(1024) void k_pre(const float* __restrict__ qg,
    const float* __restrict__ kg,
    const float* __restrict__ Wq, const float* __restrict__ bq,
    const float* __restrict__ Wk, const float* __restrict__ bk,
    uint32_t* __restrict__ qb_img, uint32_t* __restrict__ kf_img,
    float* __restrict__ kn2p, float* __restrict__ qn2p, float* __restrict__ vsp)
{
    __shared__ float buf[10240];
    int t = threadIdx.x;
    int blk = blockIdx.x;
    if (blk < 256){
        // ---------- qb projection (LDS-staged) ----------
        float* Wq_s  = buf;            // 1024
        float* q_s   = buf + 1024;     // 8192  [c][j] 32 x 256
        float* statq = buf + 9216;     // 512
        float* statv = buf + 9728;     // 512
        int bg = blk >> 1, h = blk & 1;
        int b = bg >> 6, g = bg & 63;
        int bh = g >> 4, bw = (g >> 2) & 3, bd = g & 3;
        Wq_s[t] = Wq[t];
        const float* qbase = qg + (size_t)b * 1048576;
        #pragma unroll
        for (int m = 0; m < 2; ++m){
            int L4 = m*1024 + t;
            int f4 = L4 & 1, iw = (L4 >> 1) & 7, ihl = (L4 >> 4) & 3, c = L4 >> 6;
            const float* src = qbase + c*32768 + (bh*8 + h*4 + ihl)*1024
                             + (bw*8 + iw)*32 + bd*8 + f4*4;
            float4 v = *(const float4*)src;
            *(float4*)&q_s[c*256 + ihl*64 + iw*8 + f4*4] = v;
        }
        __syncthreads();
        int d = t & 31, sub = t >> 5;      // sub 0..31
        float wq[32];
        #pragma unroll
        for (int c = 0; c < 32; ++c) wq[c] = Wq_s[c*32 + d];
        float bb = bq[d];
        uint32_t* qb_out = qb_img + (size_t)bg * 8192;
        float q2 = 0.f, vsum_ = 0.f;
        #pragma unroll
        for (int it = 0; it < 2; ++it){
            int jl = it*128 + sub*4;
            float a0 = bb, a1 = bb, a2 = bb, a3 = bb;
            #pragma unroll
            for (int c = 0; c < 32; ++c){
                float4 qv = *(const float4*)&q_s[c*256 + jl];
                a0 += qv.x*wq[c]; a1 += qv.y*wq[c];
                a2 += qv.z*wq[c]; a3 += qv.w*wq[c];
            }
            q2 += a0*a0 + a1*a1 + a2*a2 + a3*a3;
            vsum_ += a0 + a1 + a2 + a3;
            int jg = h*256 + jl;
            int grp = ((jg>>3) ^ (d&7)) & 63;
            int word = (jg&7) >> 1;
            uint2 wv; wv.x = pack2(a0, a1); wv.y = pack2(a2, a3);
            *(uint2*)&qb_out[d*256 + grp*4 + word] = wv;
        }
        // per-block norm partials (pair-reduce within wave, LDS across waves)
        q2 += __shfl_xor(q2, 32, 64);
        vsum_ += __shfl_xor(vsum_, 32, 64);
        int w = t >> 6;
        if ((t & 63) < 32){ statq[w*32 + d] = q2; statv[w*32 + d] = vsum_; }
        __syncthreads();
        if (t < 32){
            float s2 = 0.f, sv = 0.f;
            #pragma unroll
            for (int w16 = 0; w16 < 16; ++w16){
                s2 += statq[w16*32 + t];
                sv += statv[w16*32 + t];
            }
            qn2p[(bg*2 + h)*32 + t] = s2;
            vsp [(bg*2 + h)*32 + t] = sv;
        }
    } else {
        // ---------- kf projection ----------
        float* Wk_s = buf;            // 8192
        float* red  = buf + 8192;     // 1024 (32 x 32)
        for (int L = t; L < 8192; L += 1024) Wk_s[L] = Wk[L];
        __syncthreads();
        int kb_blk = blk - 256;
        int b = kb_blk >> 7, i0 = (kb_blk & 127) * 4;
        int d = t & 31, sub = t >> 5;
        int i = i0 + (sub >> 3);
        int cp = sub & 7;
        const float* kbp = kg + (size_t)b * 131072;
        float acc = 0.f;
        #pragma unroll 8
        for (int cc = 0; cc < 32; ++cc){
            int c = cp*32 + cc;
            acc += kbp[c*512 + i] * Wk_s[c*32 + d];
        }
        red[sub*32 + d] = acc;
        __syncthreads();
        if (t < 128){
            int isel = t >> 5, dd = t & 31;
            float s = bk[dd];
            #pragma unroll
            for (int cp2 = 0; cp2 < 8; ++cp2) s += red[(isel*8 + cp2)*32 + dd];
            float v2 = s*s;
            v2 += __shfl_xor(v2, 32, 64);           // combine isel pairs in-wave
            if ((t & 63) < 32)
                kn2p[b*8192 + (kb_blk & 127)*64 + (t >> 6)*32 + dd] = v2;
            float sO = __shfl_xor(s, 1, 64);
            if ((dd & 1) == 0){
                int dp = dd >> 1;
                int ii = i0 + isel;
                kf_img[b*8192 + ii*16 + (((dp>>2) ^ (ii&3)) & 3)*4 + (dp&3)] = pack2(s, sO);
            }
        }
    }
}

// ---------------- K2: MFMA attention (norm partials, no LDS prologue sweeps) --
// grid 512 = (bg, j-quarter); block 512 = 8 waves; ~66 KB LDS -> 2 blocks/CU.
// Swapped QK^T (A=kf,B=qb); exp+cvt_pk+permlane builds PV B-fragment in regs.
__global__ __launch_bounds__(512) void k_attn_mfma(const uint32_t* __restrict__ kf_img,
    const uint32_t* __restrict__ qb_img,
    const float* __restrict__ kn2p, const float* __restrict__ qn2p,
    const float* __restrict__ vsp,
    float* __restrict__ oraw, float* __restrict__ mnp, float* __restrict__ mxp)
{
    __shared__ uint32_t kfs32[8192];     // 32 KB: kf [512 i][16 dp] swizzled
    __shared__ uint16_t qbV16[16384];    // 32 KB: qb^T [32 d][512 i] swizzled
    __shared__ float mred[8][64];        // 2 KB
    __shared__ float vssh[32];
    __shared__ float denom_s;
    int t = threadIdx.x;
    int blk = blockIdx.x;
    int bg = blk >> 2, jq = blk & 3;
    int b = bg >> 6;
    int wave = t >> 6, lane = t & 63;
    // ---- stage kf + qbV: linear async copy of pre-swizzled images ----
    {
        const uint32_t* gk = kf_img + b*8192;
        const uint32_t* gq = qb_img + (size_t)bg*8192;
        uint32_t* lq = (uint32_t*)qbV16;
        #pragma unroll
        for (int m = 0; m < 4; ++m){
            int off = wave*1024 + m*256;             // u32 units; wave-uniform
            gload_lds16(gk + off + lane*4, kfs32 + off);
        }
        #pragma unroll
        for (int m = 0; m < 4; ++m){
            int off = wave*1024 + m*256;
            gload_lds16(gq + off + lane*4, lq + off);
        }
    }
    // ---- denom / vsum from fp32 partials (hidden under staging) ----
    if (t < 32){
        const float* kp = kn2p + b*8192;
        float kn = 0.f;
        #pragma unroll 8
        for (int g2 = 0; g2 < 256; ++g2) kn += kp[g2*32 + t];
        float q2 = qn2p[bg*64 + t] + qn2p[bg*64 + 32 + t];
        vssh[t]  = vsp [bg*64 + t] + vsp [bg*64 + 32 + t];
        float dv = sqrtf(kn) * sqrtf(q2);
        dv += __shfl_xor(dv, 1, 64);
        dv += __shfl_xor(dv, 2, 64);
        dv += __shfl_xor(dv, 4, 64);
        dv += __shfl_xor(dv, 8, 64);
        dv += __shfl_xor(dv, 16, 64);
        if (t == 0) denom_s = dv + 1e-4f;
    }
    __syncthreads();                     // drains gload_lds + publishes denom
    float rden = 1.0f / denom_s;
    int ln15 = lane & 15, quad = lane >> 4;
    float vs0[4], vs1[4];
    #pragma unroll
    for (int r = 0; r < 4; ++r){
        vs0[r] = vssh[quad*4 + r];
        vs1[r] = vssh[16 + quad*4 + r];
    }
    float* obase = oraw + (size_t)bg * 16384;
    int jloc = jq*128 + wave*16 + ln15;          // j within bg (0..511)
    union { bf16x8 v; uint16_t u[8]; } afr;
    #pragma unroll
    for (int jj = 0; jj < 8; ++jj){
        int d = quad*8 + jj;
        afr.u[jj] = qbV16[d*512 + (((jloc>>3) ^ (d&7)) & 63)*8 + (jloc&7)];
    }
    f32x4 pv0 = {0.f,0.f,0.f,0.f}, pv1 = {0.f,0.f,0.f,0.f};
    float pdn = 0.f;
    for (int sb = 0; sb < 4; ++sb){
        #pragma unroll
        for (int ch = 0; ch < 4; ++ch){
            int ib = sb*128 + ch*32;
            int i0 = ib + ln15;
            int i1 = i0 + 16;
            bf16x8 k0 = *(__shared__ bf16x8*)&kfs32[i0*16 + ((quad ^ (i0&3)) & 3)*4];
            bf16x8 k1 = *(__shared__ bf16x8*)&kfs32[i1*16 + ((quad ^ (i1&3)) & 3)*4];
            f32x4 z = {0.f,0.f,0.f,0.f};
            __builtin_amdgcn_s_setprio(1);
            f32x4 s0 = __builtin_amdgcn_mfma_f32_16x16x32_bf16(k0, afr.v, z, 0, 0, 0);
            f32x4 s1 = __builtin_amdgcn_mfma_f32_16x16x32_bf16(k1, afr.v, z, 0, 0, 0);
            __builtin_amdgcn_s_setprio(0);
            float e0[4], e1[4];
            #pragma unroll
            for (int r = 0; r < 4; ++r){
                float x = s0[r] * rden;
                e0[r] = x + x*x*(0.5f + x*(1.0f/6.0f));
                pdn += e0[r];
                x = s1[r] * rden;
                e1[r] = x + x*x*(0.5f + x*(1.0f/6.0f));
                pdn += e1[r];
            }
            uint32_t A0 = cvtpk(e0[0], e0[1]);
            uint32_t A1 = cvtpk(e0[2], e0[3]);
            uint32_t B0 = cvtpk(e1[0], e1[1]);
            uint32_t B1 = cvtpk(e1[2], e1[3]);
            pl32swap(A0, B0); pl16swap(A0, B0);
            pl32swap(A1, B1); pl16swap(A1, B1);
            union { bf16x8 v; uint32_t w[4]; } bp;
            bp.w[0] = A0; bp.w[1] = A1; bp.w[2] = B0; bp.w[3] = B1;
            int ig = ib + quad*8;
            int c0 = ln15, c1 = 16 + ln15;
            bf16x8 av0 = *(__shared__ bf16x8*)&qbV16[c0*512 + (((ig>>3) ^ (c0&7)) & 63)*8];
            bf16x8 av1 = *(__shared__ bf16x8*)&qbV16[c1*512 + (((ig>>3) ^ (c1&7)) & 63)*8];
            __builtin_amdgcn_s_setprio(1);
            pv0 = __builtin_amdgcn_mfma_f32_16x16x32_bf16(av0, bp.v, pv0, 0, 0, 0);
            pv1 = __builtin_amdgcn_mfma_f32_16x16x32_bf16(av1, bp.v, pv1, 0, 0, 0);
            __builtin_amdgcn_s_setprio(0);
        }
    }
    // ---- epilogue: denom (quad reduce), o write, min/max ----
    pdn += __shfl_xor(pdn, 16, 64);
    pdn += __shfl_xor(pdn, 32, 64);
    float rl = 1.0f / (512.f + pdn);
    float o0[4], o1[4];
    #pragma unroll
    for (int r = 0; r < 4; ++r){
        o0[r] = (vs0[r] + pv0[r]) * rl;
        o1[r] = (vs1[r] + pv1[r]) * rl;
        obase[(quad*4 + r)*512 + jloc]      = o0[r];
        obase[(16 + quad*4 + r)*512 + jloc] = o1[r];
    }
    #pragma unroll
    for (int r = 0; r < 4; ++r){
        float mnA = o0[r], mxA = o0[r], mnB = o1[r], mxB = o1[r];
        #pragma unroll
        for (int off = 1; off < 16; off <<= 1){
            mnA = fminf(mnA, __shfl_xor(mnA, off, 64));
            mxA = fmaxf(mxA, __shfl_xor(mxA, off, 64));
            mnB = fminf(mnB, __shfl_xor(mnB, off, 64));
            mxB = fmaxf(mxB, __shfl_xor(mxB, off, 64));
        }
        if (ln15 == 0){
            mred[wave][quad*4 + r]      = mnA;
            mred[wave][32 + quad*4 + r] = mxA;
            mred[wave][16 + quad*4 + r] = mnB;
            mred[wave][48 + quad*4 + r] = mxB;
        }
    }
    __syncthreads();
    if (t < 32){
        float mn = 3e38f, mx = -3e38f;
        #pragma unroll
        for (int w = 0; w < 8; ++w){
            mn = fminf(mn, mred[w][t]);
            mx = fmaxf(mx, mred[w][32 + t]);
        }
        int slot = (bg*4 + jq)*32 + t;
        mnp[slot] = mn;
        mxp[slot] = mx;
    }
}

// ---------------- K3: scrambled gather + fused renorm + Wp projection ----------------
// grid 2048; block 256; 32 positions/block, 4 gathers+outputs per thread
__global__ __launch_bounds__(256) void k_proj(const float* __restrict__ oraw,
    const float* __restrict__ mnp, const float* __restrict__ mxp,
    const float* __restrict__ Wp, const float* __restrict__ bp,
    float* __restrict__ out)
{
    __shared__ float Wp_s[1024], bp_s[32];
    __shared__ float sh_v[32][33];       // padded: kills 8-way bank conflict
    __shared__ float sh_o[32][33];
    int t = threadIdx.x;
    if (t < 32) bp_s[t] = bp[t];
    for (int L = t; L < 1024; L += 256) Wp_s[L] = Wp[L];
    int blk = blockIdx.x;
    int b = blk >> 10, p0 = (blk & 1023) * 32;
    int c = t & 31, ip0 = t >> 5;
    float vv[4];
    #pragma unroll
    for (int m = 0; m < 4; ++m){
        int p = p0 + m*8 + ip0;
        int h = p >> 10, w = (p >> 5) & 31, dsp = p & 31;
        int f = (h >> 3)*262144 + (w >> 3)*65536 + (dsp >> 3)*16384
              + (h & 7)*2048 + (w & 7)*256 + (dsp & 7)*32;
        int flat = f + c;
        int cidx = b*2048 + (flat >> 9);         // bg*32 + channel
        int s0 = ((cidx >> 5) << 7) + (cidx & 31);
        float o  = oraw[(size_t)b*1048576 + flat];
        float mn = fminf(fminf(mnp[s0], mnp[s0 + 32]), fminf(mnp[s0 + 64], mnp[s0 + 96]));
        float mx = fmaxf(fmaxf(mxp[s0], mxp[s0 + 32]), fmaxf(mxp[s0 + 64], mxp[s0 + 96]));
        vv[m] = (o - mn) / (mx - mn + 1e-4f);
    }
    __syncthreads();
    #pragma unroll
    for (int m = 0; m < 4; ++m) sh_v[m*8 + ip0][c] = vv[m];
    __syncthreads();
    #pragma unroll
    for (int m = 0; m < 4; ++m){
        int pos = m*8 + ip0;
        float acc = bp_s[c];
        #pragma unroll
        for (int cc = 0; cc < 32; ++cc)
            acc += sh_v[pos][cc] * Wp_s[cc*32 + c];
        sh_o[pos][c] = acc;
    }
    __syncthreads();
    #pragma unroll
    for (int m = 0; m < 4; ++m){
        int e = m*8 + (t >> 5), pi = t & 31;
        out[((size_t)(b*32 + e) << 15) + p0 + pi] = sh_o[pi][e];
    }
}

extern "C" void kernel_launch(void* const* d_in, const int* in_sizes, int n_in,
                              void* d_out, int out_size, void* d_ws, size_t ws_size,
                              hipStream_t stream)
{
    const float* q  = (const float*)d_in[0];
    const float* k  = (const float*)d_in[1];
    const float* Wq = (const float*)d_in[2];
    const float* bq = (const float*)d_in[3];
    const float* Wk = (const float*)d_in[4];
    const float* bk = (const float*)d_in[5];
    const float* Wp = (const float*)d_in[6];
    const float* bp = (const float*)d_in[7];

    float* base      = (float*)d_ws;
    uint32_t* kf_img = (uint32_t*)base;                // 16384 u32
    uint32_t* qb_img = (uint32_t*)(base + 16384);      // 1,048,576 u32
    float* oraw      = base + 1064960;                 // 2,097,152 f
    float* mnp       = base + 3162112;                 // 16384 f
    float* mxp       = base + 3178496;                 // 16384 f
    float* kn2p      = base + 3194880;                 // 16384 f
    float* qn2p      = base + 3211264;                 // 8192 f
    float* vsp       = base + 3219456;                 // 8192 f (~12.9 MB total)
    float* outp      = (float*)d_out;

    hipLaunchKernelGGL(k_pre,       dim3(512),  dim3(1024), 0, stream, q, k, Wq, bq, Wk, bk,
                       qb_img, kf_img, kn2p, qn2p, vsp);
    hipLaunchKernelGGL(k_attn_mfma, dim3(512),  dim3(512),  0, stream, kf_img, qb_img,
                       kn2p, qn2p, vsp, oraw, mnp, mxp);
    hipLaunchKernelGGL(k_proj,      dim3(2048), dim3(256),  0, stream, oraw, mnp, mxp, Wp, bp, outp);
}

// Round 10
// 114.086 us; speedup vs baseline: 1.3537x; 1.0591x over previous
//
#include <hip/hip_runtime.h>
#include <hip/hip_bf16.h>
#include <cstdint>

typedef __attribute__((ext_vector_type(8))) short bf16x8;
typedef __attribute__((ext_vector_type(4))) float f32x4;

static __device__ __forceinline__ float lo16(uint32_t u){ return __uint_as_float(u << 16); }
static __device__ __forceinline__ float hi16(uint32_t u){ return __uint_as_float(u & 0xffff0000u); }
static __device__ __forceinline__ uint32_t f2bf(float x){
    uint32_t u = __float_as_uint(x);
    return (u + 0x7fffu + ((u >> 16) & 1u)) >> 16;
}
static __device__ __forceinline__ uint32_t pack2(float a, float b){
    return f2bf(a) | (f2bf(b) << 16);
}
static __device__ __forceinline__ uint32_t cvtpk(float a, float b){
    uint32_t r;
    asm("v_cvt_pk_bf16_f32 %0, %1, %2" : "=v"(r) : "v"(a), "v"(b));
    return r;
}
static __device__ __forceinline__ void pl32swap(uint32_t &x, uint32_t &y){
    asm("v_permlane32_swap_b32 %0, %1" : "+v"(x), "+v"(y));
}
static __device__ __forceinline__ void pl16swap(uint32_t &x, uint32_t &y){
    asm("v_permlane16_swap_b32 %0, %1" : "+v"(x), "+v"(y));
}
typedef const __attribute__((address_space(1))) uint32_t* gas_u32p;
typedef __attribute__((address_space(3))) uint32_t* las_u32p;
static __device__ __forceinline__ void gload_lds16(const uint32_t* g, uint32_t* l){
    __builtin_amdgcn_global_load_lds((gas_u32p)g, (las_u32p)l, 16, 0, 0);
}

// ---------------- K1: fused kf + qb projections (R3-proven, verbatim) ---------
// grid 512: blocks 0..255 = qb (bg = blk>>1 in 0..127, j-half), 256..511 = kf.
// Image layouts (consumed linearly by k_attn_half's global_load_lds):
//   kf_img[b][8192 u32]: i*16 + (((dp>>2)^(i&3))&3)*4 + (dp&3)   (dp = d>>1)
//   qb_img[bg][8192 u32]: d*256 + (((j>>3)^(d&7))&63)*4 + ((j&7)>>1)
__global__ __launch_bounds__(1024) void k_pre(const float* __restrict__ q,
    const float* __restrict__ k,
    const float* __restrict__ Wq, const float* __restrict__ bq,
    const float* __restrict__ Wk, const float* __restrict__ bk,
    uint32_t* __restrict__ qb_img, uint32_t* __restrict__ kf_img)
{
    __shared__ float buf[9248];
    int t = threadIdx.x;
    int blk = blockIdx.x;
    if (blk < 256){
        float* Wq_s = buf;            // 1024
        float* bq_s = buf + 1024;     // 32
        float* q_s  = buf + 1056;     // 8192  [c][j] 32 x 256
        int bg = blk >> 1, h = blk & 1;
        int b = bg >> 6, g = bg & 63;
        int bh = g >> 4, bw = (g >> 2) & 3, bd = g & 3;
        Wq_s[t & 1023] = Wq[t & 1023];
        if (t < 32) bq_s[t] = bq[t];
        const float* qbase = q + (size_t)b * 1048576;
        #pragma unroll
        for (int m = 0; m < 2; ++m){
            int L4 = m*1024 + t;
            int f4 = L4 & 1, iw = (L4 >> 1) & 7, ihl = (L4 >> 4) & 3, c = L4 >> 6;
            const float* src = qbase + c*32768 + (bh*8 + h*4 + ihl)*1024
                             + (bw*8 + iw)*32 + bd*8 + f4*4;
            float4 v = *(const float4*)src;
            *(float4*)&q_s[c*256 + ihl*64 + iw*8 + f4*4] = v;
        }
        __syncthreads();
        int d = t & 31, sub = t >> 5;
        float wq[32];
        #pragma unroll
        for (int c = 0; c < 32; ++c) wq[c] = Wq_s[c*32 + d];
        uint32_t* qb_out = qb_img + (size_t)bg * 8192;
        #pragma unroll
        for (int it = 0; it < 2; ++it){
            int jl = it*128 + sub*4;
            float bb = bq_s[d];
            float a0 = bb, a1 = bb, a2 = bb, a3 = bb;
            #pragma unroll
            for (int c = 0; c < 32; ++c){
                float4 qv = *(const float4*)&q_s[c*256 + jl];
                a0 += qv.x * wq[c];
                a1 += qv.y * wq[c];
                a2 += qv.z * wq[c];
                a3 += qv.w * wq[c];
            }
            int jg = h*256 + jl;
            int grp = ((jg >> 3) ^ (d & 7)) & 63;
            int word = (jg & 7) >> 1;
            uint2 wv;
            wv.x = pack2(a0, a1);
            wv.y = pack2(a2, a3);
            *(uint2*)&qb_out[d*256 + grp*4 + word] = wv;
        }
    } else {
        float* Wk_s = buf;            // 8192
        float* bk_s = buf + 8192;     // 32
        float* red  = buf + 8224;     // 1024 (32 x 32)
        for (int L = t; L < 8192; L += 1024) Wk_s[L] = Wk[L];
        if (t < 32) bk_s[t] = bk[t];
        __syncthreads();
        int kb_blk = blk - 256;
        int b = kb_blk >> 7, i0 = (kb_blk & 127) * 4;
        int d = t & 31, sub = t >> 5;
        int i = i0 + (sub >> 3);
        int cp = sub & 7;
        const float* kbp = k + (size_t)b * 131072;
        float acc = 0.f;
        #pragma unroll 8
        for (int cc = 0; cc < 32; ++cc){
            int c = cp*32 + cc;
            acc += kbp[c*512 + i] * Wk_s[c*32 + d];
        }
        red[sub*32 + d] = acc;
        __syncthreads();
        if (t < 128){
            int isel = t >> 5, dd = t & 31;
            float s = bk_s[dd];
            #pragma unroll
            for (int cp2 = 0; cp2 < 8; ++cp2) s += red[(isel*8 + cp2)*32 + dd];
            float sO = __shfl_xor(s, 1, 64);
            if ((dd & 1) == 0){
                int dp = dd >> 1;
                int ii = i0 + isel;
                kf_img[b*8192 + ii*16 + (((dp>>2) ^ (ii&3)) & 3)*4 + (dp&3)] = pack2(s, sO);
            }
        }
    }
}

// ---------------- K2: full-bg attention + renorm + Wp, split by c_att half ----
// grid 256 = (bg in 0..127)*2 + chalf; block 512 = 8 waves; ~76 KB LDS.
// R7-R9 crash root cause fixed: bg = blk>>1 (NOT blockIdx.x with grid 256,
// which gave b = bg>>6 in 0..3 -> OOB q reads and OOB out writes -> abort).
// Block owns c_att in [chalf*16, chalf*16+16) <=> hl in chalf*4..chalf*4+3:
// min/max per c_att over all 512 j is block-local -> renorm + Wp tail fuse.
// QK^T/softmax duplicated across the pair (needs full C); PV computes only
// the block's half (the proven pv0 or pv1 path, selected by crow).
__global__ __launch_bounds__(512) void k_attn_half(
    const uint32_t* __restrict__ kf_img, const uint32_t* __restrict__ qb_img,
    const float* __restrict__ Wp, const float* __restrict__ bp,
    float* __restrict__ out)
{
    __shared__ uint32_t IMG[16384];      // 64 KB: kf[0:8192]+qbV16[8192:16384]; later v_lds f32[16][512] (32 KB)
    __shared__ float statA[1024];        // 4 KB: kn2 partials -> Wp_s (tail)
    __shared__ float statBC[1056];       // 4.2 KB: qn2/vs partials -> sh_o[32][33] (tail)
    __shared__ float mred[256];          // 1 KB: 8 waves x {mn[16], mx[16]}
    __shared__ float vssh[32];
    __shared__ float mnsh[16], rssh[16];
    __shared__ float denom_s;

    uint32_t* kfs32 = IMG;
    uint16_t* qbV16 = (uint16_t*)(IMG + 8192);
    float* v_lds = (float*)IMG;          // reuses kf region after main loop

    int t = threadIdx.x;
    int blk = blockIdx.x;
    int bg = blk >> 1, chalf = blk & 1;  // bg in 0..127
    int b = bg >> 6, g = bg & 63;
    int bh = g >> 4, bw = (g >> 2) & 3, bd = g & 3;
    int wave = t >> 6, lane = t & 63;
    int ln15 = lane & 15, quad = lane >> 4;

    // ---- stage kf + qbV: linear async copy of pre-swizzled images ----
    {
        const uint32_t* gk = kf_img + b*8192;
        const uint32_t* gq = qb_img + (size_t)bg*8192;
        uint32_t* lq = IMG + 8192;
        #pragma unroll
        for (int m = 0; m < 4; ++m){
            int off = wave*1024 + m*256;             // wave-uniform
            gload_lds16(gk + off + lane*4, kfs32 + off);
        }
        #pragma unroll
        for (int m = 0; m < 4; ++m){
            int off = wave*1024 + m*256;
            gload_lds16(gq + off + lane*4, lq + off);
        }
    }
    __syncthreads();
    // ---- prologue sweeps: knorm2 / qn2 / vsum (R3-proven) ----
    {
        int dp = t & 15, ig = t >> 4;            // 32 groups of 16 i
        float lo2 = 0.f, hi2 = 0.f;
        #pragma unroll
        for (int ii = 0; ii < 16; ++ii){
            int i = ig*16 + ii;
            uint32_t u = kfs32[i*16 + (((dp>>2) ^ (i&3)) & 3)*4 + (dp&3)];
            float a = lo16(u), c = hi16(u);
            lo2 += a*a; hi2 += c*c;
        }
        statA[ig*32 + dp*2] = lo2; statA[ig*32 + dp*2 + 1] = hi2;
    }
    {
        int d = t & 31, ig = t >> 5;             // 16 groups of 32 i
        float q2 = 0.f, vs = 0.f;
        #pragma unroll
        for (int ii = 0; ii < 32; ii += 2){
            int i = ig*32 + ii;
            uint32_t u = *(__shared__ uint32_t*)&qbV16[d*512 + (((i>>3) ^ (d&7)) & 63)*8 + (i&7)];
            float a = lo16(u), c = hi16(u);
            q2 += a*a + c*c; vs += a + c;
        }
        statBC[ig*32 + d] = q2; statBC[512 + ig*32 + d] = vs;
    }
    __syncthreads();
    if (t < 32){
        float kn = 0.f;
        #pragma unroll
        for (int u = 0; u < 32; ++u) kn += statA[u*32 + t];
        float q2 = 0.f, vs = 0.f;
        #pragma unroll
        for (int u = 0; u < 16; ++u){ q2 += statBC[u*32 + t]; vs += statBC[512 + u*32 + t]; }
        vssh[t] = vs;
        float dv = sqrtf(kn) * sqrtf(q2);
        dv += __shfl_xor(dv, 1, 64);
        dv += __shfl_xor(dv, 2, 64);
        dv += __shfl_xor(dv, 4, 64);
        dv += __shfl_xor(dv, 8, 64);
        dv += __shfl_xor(dv, 16, 64);
        if (t == 0) denom_s = dv + 1e-4f;
    }
    __syncthreads();
    float rden = 1.0f / denom_s;
    float vs_sel[4];
    #pragma unroll
    for (int r = 0; r < 4; ++r)
        vs_sel[r] = vssh[chalf*16 + quad*4 + r];
    // ---- main: 4 j-quarters in-block; PV for this block's c-half only ----
    float oq[4][4];
    float mn[4], mx[4];
    #pragma unroll
    for (int r = 0; r < 4; ++r){ mn[r] = 3e38f; mx[r] = -3e38f; }
    int crow = chalf*16 + ln15;                      // PV A-operand row
    #pragma unroll
    for (int jq = 0; jq < 4; ++jq){
        int jloc = jq*128 + wave*16 + ln15;          // 0..511
        union { bf16x8 v; uint16_t u[8]; } afr;
        #pragma unroll
        for (int jj = 0; jj < 8; ++jj){
            int d = quad*8 + jj;
            afr.u[jj] = qbV16[d*512 + (((jloc>>3) ^ (d&7)) & 63)*8 + (jloc&7)];
        }
        f32x4 pv = {0.f,0.f,0.f,0.f};
        float pdn = 0.f;
        for (int sb = 0; sb < 4; ++sb){
            #pragma unroll
            for (int ch = 0; ch < 4; ++ch){
                int ib = sb*128 + ch*32;
                int i0 = ib + ln15;
                int i1 = i0 + 16;
                bf16x8 k0 = *(__shared__ bf16x8*)&kfs32[i0*16 + ((quad ^ (i0&3)) & 3)*4];
                bf16x8 k1 = *(__shared__ bf16x8*)&kfs32[i1*16 + ((quad ^ (i1&3)) & 3)*4];
                f32x4 z = {0.f,0.f,0.f,0.f};
                f32x4 s0 = __builtin_amdgcn_mfma_f32_16x16x32_bf16(k0, afr.v, z, 0, 0, 0);
                f32x4 s1 = __builtin_amdgcn_mfma_f32_16x16x32_bf16(k1, afr.v, z, 0, 0, 0);
                float e0[4], e1[4];
                #pragma unroll
                for (int r = 0; r < 4; ++r){
                    float x = s0[r] * rden;
                    e0[r] = x + x*x*(0.5f + x*(1.0f/6.0f));
                    pdn += e0[r];
                    x = s1[r] * rden;
                    e1[r] = x + x*x*(0.5f + x*(1.0f/6.0f));
                    pdn += e1[r];
                }
                uint32_t A0 = cvtpk(e0[0], e0[1]);
                uint32_t A1 = cvtpk(e0[2], e0[3]);
                uint32_t B0 = cvtpk(e1[0], e1[1]);
                uint32_t B1 = cvtpk(e1[2], e1[3]);
                pl32swap(A0, B0); pl16swap(A0, B0);
                pl32swap(A1, B1); pl16swap(A1, B1);
                union { bf16x8 v; uint32_t w[4]; } bpv;
                bpv.w[0] = A0; bpv.w[1] = A1; bpv.w[2] = B0; bpv.w[3] = B1;
                int ig = ib + quad*8;
                bf16x8 av = *(__shared__ bf16x8*)&qbV16[crow*512 + (((ig>>3) ^ (crow&7)) & 63)*8];
                pv = __builtin_amdgcn_mfma_f32_16x16x32_bf16(av, bpv.v, pv, 0, 0, 0);
            }
        }
        pdn += __shfl_xor(pdn, 16, 64);
        pdn += __shfl_xor(pdn, 32, 64);
        float rl = 1.0f / (512.f + pdn);
        #pragma unroll
        for (int r = 0; r < 4; ++r){
            float o = (vs_sel[r] + pv[r]) * rl;
            oq[jq][r] = o;
            mn[r] = fminf(mn[r], o);
            mx[r] = fmaxf(mx[r], o);
        }
    }
    // ---- block-local min/max (16 c_att) ----
    #pragma unroll
    for (int r = 0; r < 4; ++r){
        #pragma unroll
        for (int off = 1; off < 16; off <<= 1){
            mn[r] = fminf(mn[r], __shfl_xor(mn[r], off, 64));
            mx[r] = fmaxf(mx[r], __shfl_xor(mx[r], off, 64));
        }
        if (ln15 == 0){
            mred[wave*32 + quad*4 + r]      = mn[r];
            mred[wave*32 + 16 + quad*4 + r] = mx[r];
        }
    }
    __syncthreads();                     // all IMG reads done; mred published
    if (t < 16){
        float m0 = 3e38f, m1 = -3e38f;
        #pragma unroll
        for (int w = 0; w < 8; ++w){
            m0 = fminf(m0, mred[w*32 + t]);
            m1 = fmaxf(m1, mred[w*32 + 16 + t]);
        }
        mnsh[t] = m0;
        rssh[t] = 1.0f / (m1 - m0 + 1e-4f);
    }
    __syncthreads();
    // ---- renorm o (regs) -> v_lds [16 c][512 j]; stage Wp ----
    {
        float mnr[4], rsr[4];
        #pragma unroll
        for (int r = 0; r < 4; ++r){
            mnr[r] = mnsh[quad*4 + r];
            rsr[r] = rssh[quad*4 + r];
        }
        #pragma unroll
        for (int jq = 0; jq < 4; ++jq){
            int j = jq*128 + wave*16 + ln15;
            #pragma unroll
            for (int r = 0; r < 4; ++r)
                v_lds[(quad*4 + r)*512 + j] = (oq[jq][r] - mnr[r]) * rsr[r];
        }
        statA[t] = Wp[t];
        statA[512 + t] = Wp[512 + t];
    }
    __syncthreads();
    // ---- tail: Wp GEMM + transposed coalesced stores (8 passes) ----
    {
        int e = t & 31;
        float bpv = bp[e];
        for (int pass = 0; pass < 8; ++pass){
            #pragma unroll
            for (int ii = 0; ii < 2; ++ii){
                int pl = ii*16 + (t >> 5);           // 0..31
                int P = pass*32 + pl;                // 0..255
                int c_v = P >> 4, j_hi = P & 15;     // c_v local 0..15
                const float* vrow = &v_lds[c_v*512 + j_hi*32];
                float S = bpv;
                #pragma unroll
                for (int c4 = 0; c4 < 8; ++c4){
                    float4 vv4 = *(float4*)&vrow[c4*4];
                    S += vv4.x * statA[(c4*4    )*32 + e]
                       + vv4.y * statA[(c4*4 + 1)*32 + e]
                       + vv4.z * statA[(c4*4 + 2)*32 + e]
                       + vv4.w * statA[(c4*4 + 3)*32 + e];
                }
                statBC[pl*33 + e] = S;
            }
            __syncthreads();
            {
                int d_low = t & 7, e2 = (t >> 3) & 31, hi2 = t >> 8;   // hi2 in {0,1}
                #pragma unroll
                for (int m2 = 0; m2 < 2; ++m2){
                    int pl = hi2*16 + m2*8 + d_low;
                    int c_v = pass*2 + hi2;          // local
                    float val = statBC[pl*33 + e2];
                    int cg = chalf*16 + c_v;         // global c_att
                    int hl = cg >> 2, wl = (c_v & 3)*2 + m2;
                    out[((size_t)(b*32 + e2) << 15)
                        + (bh*8 + hl)*1024 + (bw*8 + wl)*32 + bd*8 + d_low] = val;
                }
            }
            __syncthreads();
        }
    }
}

extern "C" void kernel_launch(void* const* d_in, const int* in_sizes, int n_in,
                              void* d_out, int out_size, void* d_ws, size_t ws_size,
                              hipStream_t stream)
{
    const float* q  = (const float*)d_in[0];
    const float* k  = (const float*)d_in[1];
    const float* Wq = (const float*)d_in[2];
    const float* bq = (const float*)d_in[3];
    const float* Wk = (const float*)d_in[4];
    const float* bk = (const float*)d_in[5];
    const float* Wp = (const float*)d_in[6];
    const float* bp = (const float*)d_in[7];

    uint32_t* kf_img = (uint32_t*)d_ws;                  // 16384 u32
    uint32_t* qb_img = (uint32_t*)d_ws + 16384;          // 1,048,576 u32 (~4.3 MB total)
    float* outp      = (float*)d_out;

    hipLaunchKernelGGL(k_pre,       dim3(512), dim3(1024), 0, stream, q, k, Wq, bq, Wk, bk,
                       qb_img, kf_img);
    hipLaunchKernelGGL(k_attn_half, dim3(256), dim3(512),  0, stream, kf_img, qb_img,
                       Wp, bp, outp);
}

// Round 11
// 112.475 us; speedup vs baseline: 1.3731x; 1.0143x over previous
//
#include <hip/hip_runtime.h>
#include <hip/hip_bf16.h>
#include <cstdint>

typedef __attribute__((ext_vector_type(8))) short bf16x8;
typedef __attribute__((ext_vector_type(4))) float f32x4;

static __device__ __forceinline__ float lo16(uint32_t u){ return __uint_as_float(u << 16); }
static __device__ __forceinline__ float hi16(uint32_t u){ return __uint_as_float(u & 0xffff0000u); }
static __device__ __forceinline__ uint32_t f2bf(float x){
    uint32_t u = __float_as_uint(x);
    return (u + 0x7fffu + ((u >> 16) & 1u)) >> 16;
}
static __device__ __forceinline__ uint32_t pack2(float a, float b){
    return f2bf(a) | (f2bf(b) << 16);
}
static __device__ __forceinline__ uint32_t cvtpk(float a, float b){
    uint32_t r;
    asm("v_cvt_pk_bf16_f32 %0, %1, %2" : "=v"(r) : "v"(a), "v"(b));
    return r;
}
static __device__ __forceinline__ void pl32swap(uint32_t &x, uint32_t &y){
    asm("v_permlane32_swap_b32 %0, %1" : "+v"(x), "+v"(y));
}
static __device__ __forceinline__ void pl16swap(uint32_t &x, uint32_t &y){
    asm("v_permlane16_swap_b32 %0, %1" : "+v"(x), "+v"(y));
}
typedef const __attribute__((address_space(1))) uint32_t* gas_u32p;
typedef __attribute__((address_space(3))) uint32_t* las_u32p;
static __device__ __forceinline__ void gload_lds16(const uint32_t* g, uint32_t* l){
    __builtin_amdgcn_global_load_lds((gas_u32p)g, (las_u32p)l, 16, 0, 0);
}

// ---------------- K1: fused kf + qb projections (R10-proven, verbatim) --------
// grid 512: blocks 0..255 = qb (bg = blk>>1 in 0..127, j-half), 256..511 = kf.
// Image layouts (consumed linearly by k_attn_half's global_load_lds):
//   kf_img[b][8192 u32]: i*16 + (((dp>>2)^(i&3))&3)*4 + (dp&3)   (dp = d>>1)
//   qb_img[bg][8192 u32]: d*256 + (((j>>3)^(d&7))&63)*4 + ((j&7)>>1)
__global__ __launch_bounds__(1024) void k_pre(const float* __restrict__ q,
    const float* __restrict__ k,
    const float* __restrict__ Wq, const float* __restrict__ bq,
    const float* __restrict__ Wk, const float* __restrict__ bk,
    uint32_t* __restrict__ qb_img, uint32_t* __restrict__ kf_img)
{
    __shared__ float buf[9248];
    int t = threadIdx.x;
    int blk = blockIdx.x;
    if (blk < 256){
        float* Wq_s = buf;            // 1024
        float* bq_s = buf + 1024;     // 32
        float* q_s  = buf + 1056;     // 8192  [c][j] 32 x 256
        int bg = blk >> 1, h = blk & 1;
        int b = bg >> 6, g = bg & 63;
        int bh = g >> 4, bw = (g >> 2) & 3, bd = g & 3;
        Wq_s[t & 1023] = Wq[t & 1023];
        if (t < 32) bq_s[t] = bq[t];
        const float* qbase = q + (size_t)b * 1048576;
        #pragma unroll
        for (int m = 0; m < 2; ++m){
            int L4 = m*1024 + t;
            int f4 = L4 & 1, iw = (L4 >> 1) & 7, ihl = (L4 >> 4) & 3, c = L4 >> 6;
            const float* src = qbase + c*32768 + (bh*8 + h*4 + ihl)*1024
                             + (bw*8 + iw)*32 + bd*8 + f4*4;
            float4 v = *(const float4*)src;
            *(float4*)&q_s[c*256 + ihl*64 + iw*8 + f4*4] = v;
        }
        __syncthreads();
        int d = t & 31, sub = t >> 5;
        float wq[32];
        #pragma unroll
        for (int c = 0; c < 32; ++c) wq[c] = Wq_s[c*32 + d];
        uint32_t* qb_out = qb_img + (size_t)bg * 8192;
        #pragma unroll
        for (int it = 0; it < 2; ++it){
            int jl = it*128 + sub*4;
            float bb = bq_s[d];
            float a0 = bb, a1 = bb, a2 = bb, a3 = bb;
            #pragma unroll
            for (int c = 0; c < 32; ++c){
                float4 qv = *(const float4*)&q_s[c*256 + jl];
                a0 += qv.x * wq[c];
                a1 += qv.y * wq[c];
                a2 += qv.z * wq[c];
                a3 += qv.w * wq[c];
            }
            int jg = h*256 + jl;
            int grp = ((jg >> 3) ^ (d & 7)) & 63;
            int word = (jg & 7) >> 1;
            uint2 wv;
            wv.x = pack2(a0, a1);
            wv.y = pack2(a2, a3);
            *(uint2*)&qb_out[d*256 + grp*4 + word] = wv;
        }
    } else {
        float* Wk_s = buf;            // 8192
        float* bk_s = buf + 8192;     // 32
        float* red  = buf + 8224;     // 1024 (32 x 32)
        for (int L = t; L < 8192; L += 1024) Wk_s[L] = Wk[L];
        if (t < 32) bk_s[t] = bk[t];
        __syncthreads();
        int kb_blk = blk - 256;
        int b = kb_blk >> 7, i0 = (kb_blk & 127) * 4;
        int d = t & 31, sub = t >> 5;
        int i = i0 + (sub >> 3);
        int cp = sub & 7;
        const float* kbp = k + (size_t)b * 131072;
        float acc = 0.f;
        #pragma unroll 8
        for (int cc = 0; cc < 32; ++cc){
            int c = cp*32 + cc;
            acc += kbp[c*512 + i] * Wk_s[c*32 + d];
        }
        red[sub*32 + d] = acc;
        __syncthreads();
        if (t < 128){
            int isel = t >> 5, dd = t & 31;
            float s = bk_s[dd];
            #pragma unroll
            for (int cp2 = 0; cp2 < 8; ++cp2) s += red[(isel*8 + cp2)*32 + dd];
            float sO = __shfl_xor(s, 1, 64);
            if ((dd & 1) == 0){
                int dp = dd >> 1;
                int ii = i0 + isel;
                kf_img[b*8192 + ii*16 + (((dp>>2) ^ (ii&3)) & 3)*4 + (dp&3)] = pack2(s, sO);
            }
        }
    }
}

// ---------------- K2: full-bg attention + renorm + Wp, split by c_att half ----
// grid 256 = (bg in 0..127)*2 + chalf; block 512 = 8 waves; ~76 KB LDS.
// Change vs R10: the wave's 4 j-tiles processed in PAIRS -- one (k0,k1,av)
// LDS load triple feeds both tiles' QK and PV MFMAs, halving main-loop
// ds_read_b128 count (192 -> 96 per wave). Arithmetic identical.
__global__ __launch_bounds__(512) void k_attn_half(
    const uint32_t* __restrict__ kf_img, const uint32_t* __restrict__ qb_img,
    const float* __restrict__ Wp, const float* __restrict__ bp,
    float* __restrict__ out)
{
    __shared__ uint32_t IMG[16384];      // 64 KB: kf[0:8192]+qbV16[8192:16384]; later v_lds f32[16][512]
    __shared__ float statA[1024];        // 4 KB: kn2 partials -> Wp_s (tail)
    __shared__ float statBC[1056];       // 4.2 KB: qn2/vs partials -> sh_o[32][33] (tail)
    __shared__ float mred[256];          // 1 KB: 8 waves x {mn[16], mx[16]}
    __shared__ float vssh[32];
    __shared__ float mnsh[16], rssh[16];
    __shared__ float denom_s;

    uint32_t* kfs32 = IMG;
    uint16_t* qbV16 = (uint16_t*)(IMG + 8192);
    float* v_lds = (float*)IMG;          // reuses kf region after main loop

    int t = threadIdx.x;
    int blk = blockIdx.x;
    int bg = blk >> 1, chalf = blk & 1;  // bg in 0..127
    int b = bg >> 6, g = bg & 63;
    int bh = g >> 4, bw = (g >> 2) & 3, bd = g & 3;
    int wave = t >> 6, lane = t & 63;
    int ln15 = lane & 15, quad = lane >> 4;

    // ---- stage kf + qbV: linear async copy of pre-swizzled images ----
    {
        const uint32_t* gk = kf_img + b*8192;
        const uint32_t* gq = qb_img + (size_t)bg*8192;
        uint32_t* lq = IMG + 8192;
        #pragma unroll
        for (int m = 0; m < 4; ++m){
            int off = wave*1024 + m*256;             // wave-uniform
            gload_lds16(gk + off + lane*4, kfs32 + off);
        }
        #pragma unroll
        for (int m = 0; m < 4; ++m){
            int off = wave*1024 + m*256;
            gload_lds16(gq + off + lane*4, lq + off);
        }
    }
    __syncthreads();
    // ---- prologue sweeps: knorm2 / qn2 / vsum (R3-proven) ----
    {
        int dp = t & 15, ig = t >> 4;            // 32 groups of 16 i
        float lo2 = 0.f, hi2 = 0.f;
        #pragma unroll
        for (int ii = 0; ii < 16; ++ii){
            int i = ig*16 + ii;
            uint32_t u = kfs32[i*16 + (((dp>>2) ^ (i&3)) & 3)*4 + (dp&3)];
            float a = lo16(u), c = hi16(u);
            lo2 += a*a; hi2 += c*c;
        }
        statA[ig*32 + dp*2] = lo2; statA[ig*32 + dp*2 + 1] = hi2;
    }
    {
        int d = t & 31, ig = t >> 5;             // 16 groups of 32 i
        float q2 = 0.f, vs = 0.f;
        #pragma unroll
        for (int ii = 0; ii < 32; ii += 2){
            int i = ig*32 + ii;
            uint32_t u = *(__shared__ uint32_t*)&qbV16[d*512 + (((i>>3) ^ (d&7)) & 63)*8 + (i&7)];
            float a = lo16(u), c = hi16(u);
            q2 += a*a + c*c; vs += a + c;
        }
        statBC[ig*32 + d] = q2; statBC[512 + ig*32 + d] = vs;
    }
    __syncthreads();
    if (t < 32){
        float kn = 0.f;
        #pragma unroll
        for (int u = 0; u < 32; ++u) kn += statA[u*32 + t];
        float q2 = 0.f, vs = 0.f;
        #pragma unroll
        for (int u = 0; u < 16; ++u){ q2 += statBC[u*32 + t]; vs += statBC[512 + u*32 + t]; }
        vssh[t] = vs;
        float dv = sqrtf(kn) * sqrtf(q2);
        dv += __shfl_xor(dv, 1, 64);
        dv += __shfl_xor(dv, 2, 64);
        dv += __shfl_xor(dv, 4, 64);
        dv += __shfl_xor(dv, 8, 64);
        dv += __shfl_xor(dv, 16, 64);
        if (t == 0) denom_s = dv + 1e-4f;
    }
    __syncthreads();
    float rden = 1.0f / denom_s;
    float vs_sel[4];
    #pragma unroll
    for (int r = 0; r < 4; ++r)
        vs_sel[r] = vssh[chalf*16 + quad*4 + r];
    // ---- main: j-tiles in pairs; PV for this block's c-half only ----
    float oq[4][4];
    float mn[4], mx[4];
    #pragma unroll
    for (int r = 0; r < 4; ++r){ mn[r] = 3e38f; mx[r] = -3e38f; }
    int crow = chalf*16 + ln15;                      // PV A-operand row
    #pragma unroll
    for (int jp = 0; jp < 2; ++jp){
        int jlocA = (jp*2    )*128 + wave*16 + ln15;
        int jlocB = (jp*2 + 1)*128 + wave*16 + ln15;
        union { bf16x8 v; uint16_t u[8]; } afrA, afrB;
        #pragma unroll
        for (int jj = 0; jj < 8; ++jj){
            int d = quad*8 + jj;
            afrA.u[jj] = qbV16[d*512 + (((jlocA>>3) ^ (d&7)) & 63)*8 + (jlocA&7)];
            afrB.u[jj] = qbV16[d*512 + (((jlocB>>3) ^ (d&7)) & 63)*8 + (jlocB&7)];
        }
        f32x4 pvA = {0.f,0.f,0.f,0.f}, pvB = {0.f,0.f,0.f,0.f};
        float pdnA = 0.f, pdnB = 0.f;
        for (int sb = 0; sb < 4; ++sb){
            #pragma unroll
            for (int ch = 0; ch < 4; ++ch){
                int ib = sb*128 + ch*32;
                int i0 = ib + ln15;
                int i1 = i0 + 16;
                bf16x8 k0 = *(__shared__ bf16x8*)&kfs32[i0*16 + ((quad ^ (i0&3)) & 3)*4];
                bf16x8 k1 = *(__shared__ bf16x8*)&kfs32[i1*16 + ((quad ^ (i1&3)) & 3)*4];
                f32x4 z = {0.f,0.f,0.f,0.f};
                f32x4 sA0 = __builtin_amdgcn_mfma_f32_16x16x32_bf16(k0, afrA.v, z, 0, 0, 0);
                f32x4 sA1 = __builtin_amdgcn_mfma_f32_16x16x32_bf16(k1, afrA.v, z, 0, 0, 0);
                f32x4 sB0 = __builtin_amdgcn_mfma_f32_16x16x32_bf16(k0, afrB.v, z, 0, 0, 0);
                f32x4 sB1 = __builtin_amdgcn_mfma_f32_16x16x32_bf16(k1, afrB.v, z, 0, 0, 0);
                float eA0[4], eA1[4], eB0[4], eB1[4];
                #pragma unroll
                for (int r = 0; r < 4; ++r){
                    float x = sA0[r] * rden;
                    eA0[r] = x + x*x*(0.5f + x*(1.0f/6.0f));
                    pdnA += eA0[r];
                    x = sA1[r] * rden;
                    eA1[r] = x + x*x*(0.5f + x*(1.0f/6.0f));
                    pdnA += eA1[r];
                    x = sB0[r] * rden;
                    eB0[r] = x + x*x*(0.5f + x*(1.0f/6.0f));
                    pdnB += eB0[r];
                    x = sB1[r] * rden;
                    eB1[r] = x + x*x*(0.5f + x*(1.0f/6.0f));
                    pdnB += eB1[r];
                }
                uint32_t A0 = cvtpk(eA0[0], eA0[1]);
                uint32_t A1 = cvtpk(eA0[2], eA0[3]);
                uint32_t C0 = cvtpk(eA1[0], eA1[1]);
                uint32_t C1 = cvtpk(eA1[2], eA1[3]);
                pl32swap(A0, C0); pl16swap(A0, C0);
                pl32swap(A1, C1); pl16swap(A1, C1);
                union { bf16x8 v; uint32_t w[4]; } bpA;
                bpA.w[0] = A0; bpA.w[1] = A1; bpA.w[2] = C0; bpA.w[3] = C1;
                uint32_t B0 = cvtpk(eB0[0], eB0[1]);
                uint32_t B1 = cvtpk(eB0[2], eB0[3]);
                uint32_t D0 = cvtpk(eB1[0], eB1[1]);
                uint32_t D1 = cvtpk(eB1[2], eB1[3]);
                pl32swap(B0, D0); pl16swap(B0, D0);
                pl32swap(B1, D1); pl16swap(B1, D1);
                union { bf16x8 v; uint32_t w[4]; } bpB;
                bpB.w[0] = B0; bpB.w[1] = B1; bpB.w[2] = D0; bpB.w[3] = D1;
                int ig = ib + quad*8;
                bf16x8 av = *(__shared__ bf16x8*)&qbV16[crow*512 + (((ig>>3) ^ (crow&7)) & 63)*8];
                pvA = __builtin_amdgcn_mfma_f32_16x16x32_bf16(av, bpA.v, pvA, 0, 0, 0);
                pvB = __builtin_amdgcn_mfma_f32_16x16x32_bf16(av, bpB.v, pvB, 0, 0, 0);
            }
        }
        pdnA += __shfl_xor(pdnA, 16, 64);
        pdnA += __shfl_xor(pdnA, 32, 64);
        pdnB += __shfl_xor(pdnB, 16, 64);
        pdnB += __shfl_xor(pdnB, 32, 64);
        float rlA = 1.0f / (512.f + pdnA);
        float rlB = 1.0f / (512.f + pdnB);
        #pragma unroll
        for (int r = 0; r < 4; ++r){
            float oA = (vs_sel[r] + pvA[r]) * rlA;
            float oB = (vs_sel[r] + pvB[r]) * rlB;
            oq[jp*2][r]     = oA;
            oq[jp*2 + 1][r] = oB;
            mn[r] = fminf(mn[r], fminf(oA, oB));
            mx[r] = fmaxf(mx[r], fmaxf(oA, oB));
        }
    }
    // ---- block-local min/max (16 c_att) ----
    #pragma unroll
    for (int r = 0; r < 4; ++r){
        #pragma unroll
        for (int off = 1; off < 16; off <<= 1){
            mn[r] = fminf(mn[r], __shfl_xor(mn[r], off, 64));
            mx[r] = fmaxf(mx[r], __shfl_xor(mx[r], off, 64));
        }
        if (ln15 == 0){
            mred[wave*32 + quad*4 + r]      = mn[r];
            mred[wave*32 + 16 + quad*4 + r] = mx[r];
        }
    }
    __syncthreads();                     // all IMG reads done; mred published
    if (t < 16){
        float m0 = 3e38f, m1 = -3e38f;
        #pragma unroll
        for (int w = 0; w < 8; ++w){
            m0 = fminf(m0, mred[w*32 + t]);
            m1 = fmaxf(m1, mred[w*32 + 16 + t]);
        }
        mnsh[t] = m0;
        rssh[t] = 1.0f / (m1 - m0 + 1e-4f);
    }
    __syncthreads();
    // ---- renorm o (regs) -> v_lds [16 c][512 j]; stage Wp ----
    {
        float mnr[4], rsr[4];
        #pragma unroll
        for (int r = 0; r < 4; ++r){
            mnr[r] = mnsh[quad*4 + r];
            rsr[r] = rssh[quad*4 + r];
        }
        #pragma unroll
        for (int jq = 0; jq < 4; ++jq){
            int j = jq*128 + wave*16 + ln15;
            #pragma unroll
            for (int r = 0; r < 4; ++r)
                v_lds[(quad*4 + r)*512 + j] = (oq[jq][r] - mnr[r]) * rsr[r];
        }
        statA[t] = Wp[t];
        statA[512 + t] = Wp[512 + t];
    }
    __syncthreads();
    // ---- tail: Wp GEMM + transposed coalesced stores (8 passes) ----
    {
        int e = t & 31;
        float bpv = bp[e];
        for (int pass = 0; pass < 8; ++pass){
            #pragma unroll
            for (int ii = 0; ii < 2; ++ii){
                int pl = ii*16 + (t >> 5);           // 0..31
                int P = pass*32 + pl;                // 0..255
                int c_v = P >> 4, j_hi = P & 15;     // c_v local 0..15
                const float* vrow = &v_lds[c_v*512 + j_hi*32];
                float S = bpv;
                #pragma unroll
                for (int c4 = 0; c4 < 8; ++c4){
                    float4 vv4 = *(float4*)&vrow[c4*4];
                    S += vv4.x * statA[(c4*4    )*32 + e]
                       + vv4.y * statA[(c4*4 + 1)*32 + e]
                       + vv4.z * statA[(c4*4 + 2)*32 + e]
                       + vv4.w * statA[(c4*4 + 3)*32 + e];
                }
                statBC[pl*33 + e] = S;
            }
            __syncthreads();
            {
                int d_low = t & 7, e2 = (t >> 3) & 31, hi2 = t >> 8;   // hi2 in {0,1}
                #pragma unroll
                for (int m2 = 0; m2 < 2; ++m2){
                    int pl = hi2*16 + m2*8 + d_low;
                    int c_v = pass*2 + hi2;          // local
                    float val = statBC[pl*33 + e2];
                    int cg = chalf*16 + c_v;         // global c_att
                    int hl = cg >> 2, wl = (c_v & 3)*2 + m2;
                    out[((size_t)(b*32 + e2) << 15)
                        + (bh*8 + hl)*1024 + (bw*8 + wl)*32 + bd*8 + d_low] = val;
                }
            }
            __syncthreads();
        }
    }
}

extern "C" void kernel_launch(void* const* d_in, const int* in_sizes, int n_in,
                              void* d_out, int out_size, void* d_ws, size_t ws_size,
                              hipStream_t stream)
{
    const float* q  = (const float*)d_in[0];
    const float* k  = (const float*)d_in[1];
    const float* Wq = (const float*)d_in[2];
    const float* bq = (const float*)d_in[3];
    const float* Wk = (const float*)d_in[4];
    const float* bk = (const float*)d_in[5];
    const float* Wp = (const float*)d_in[6];
    const float* bp = (const float*)d_in[7];

    uint32_t* kf_img = (uint32_t*)d_ws;                  // 16384 u32
    uint32_t* qb_img = (uint32_t*)d_ws + 16384;          // 1,048,576 u32 (~4.3 MB total)
    float* outp      = (float*)d_out;

    hipLaunchKernelGGL(k_pre,       dim3(512), dim3(1024), 0, stream, q, k, Wq, bq, Wk, bk,
                       qb_img, kf_img);
    hipLaunchKernelGGL(k_attn_half, dim3(256), dim3(512),  0, stream, kf_img, qb_img,
                       Wp, bp, outp);
}